// Round 12
// baseline (119.510 us; speedup 1.0000x reference)
//
#include <hip/hip_runtime.h>
#include <hip/hip_bf16.h>

// MoE top-1: N=16384 tokens, D=1024, E=8 experts.
// out[n] = expert_w[argmax(router(x[n]))] @ x[n] + expert_b[e]
//
// Pipeline: convw -> router (rw in LDS, token-pair ILP, f64 in-lane dots +
// f32 cross-lane reduce, fused x->bf16, no atomics) -> single-block counting
// sort -> grouped bf16-MFMA GEMM (256x256 tile, 8 waves, 8-phase-per-2-K-tile
// schedule: per-phase {ds_read || gload_lds prefetch || MFMA} with raw
// barriers, lgkmcnt(0)+sched_barrier, setprio around MFMA; XOR-swizzled LDS;
// expert->XCD swizzle).

#define NTOK 16384
#define DIM  1024
#define NEXP 8

#define AS1 __attribute__((address_space(1)))
#define AS3 __attribute__((address_space(3)))

typedef __bf16 bf16x8 __attribute__((ext_vector_type(8)));
typedef float  f32x4  __attribute__((ext_vector_type(4)));

__device__ __forceinline__ unsigned int f2bf(float f) {
  unsigned int u = __builtin_bit_cast(unsigned int, f);
  u += 0x7FFFu + ((u >> 16) & 1u);   // round-to-nearest-even (finite inputs)
  return u >> 16;
}

// expert_w f32 -> bf16, 8 elements per thread. grid 4096 x 256.
__global__ __launch_bounds__(256) void k_convw(const float* __restrict__ src,
                                               unsigned short* __restrict__ dst) {
  size_t i = ((size_t)blockIdx.x * 256 + threadIdx.x) * 8;
  const float4* p = (const float4*)(src + i);
  float4 a = p[0], b = p[1];
  unsigned int w0 = f2bf(a.x) | (f2bf(a.y) << 16);
  unsigned int w1 = f2bf(a.z) | (f2bf(a.w) << 16);
  unsigned int w2 = f2bf(b.x) | (f2bf(b.y) << 16);
  unsigned int w3 = f2bf(b.z) | (f2bf(b.w) << 16);
  *(uint4*)(dst + i) = make_uint4(w0, w1, w2, w3);
}

// Router: rw (32 KB) staged in LDS once per block. Lane l owns x elements
// {j*256 + 4l .. +4}, j=0..3 (16 B/lane stride => conflict-free ds_read_b128).
// TWO tokens per w-fragment read. j-OUTER / e-INNER with a sched_barrier(0)
// after each j caps live w-fragments (~8 VGPRs). In-lane partials in f64
// (f32 products exact => argmax ground-truth); cross-lane reduce in f32
// (err ~3e-7 << np's own f32 noise). Fused x->bf16. No atomics.
__global__ __launch_bounds__(256) void k_router(const float* __restrict__ x,
                                                const float* __restrict__ rw,
                                                const float* __restrict__ rb,
                                                unsigned short* __restrict__ xbf,
                                                int* __restrict__ top) {
  __shared__ float wlds[NEXP * DIM];   // 32 KB
  const int tid = threadIdx.x;
  const int lane = tid & 63;
  const int wave = tid >> 6;
#pragma unroll
  for (int i = 0; i < 8; ++i)
    ((float4*)wlds)[tid + 256 * i] = ((const float4*)rw)[tid + 256 * i];
  __syncthreads();

  const int ea = lane & 7;
  const float bias = rb[ea];

#pragma unroll 1
  for (int tp = 0; tp < 2; ++tp) {     // two token-pairs per wave (4 tokens)
    const int nA = (blockIdx.x << 4) + (wave << 2) + (tp << 1);
    const int nB = nA + 1;

    float4 xa[4], xb[4];
#pragma unroll
    for (int j = 0; j < 4; ++j) {      // 8 independent 16B loads (deep MLP)
      xa[j] = *(const float4*)(x + ((size_t)nA << 10) + (j << 8) + (lane << 2));
      xb[j] = *(const float4*)(x + ((size_t)nB << 10) + (j << 8) + (lane << 2));
    }

    // fused bf16 conversion + store: 8 B/lane per (token,j), coalesced 512 B
#pragma unroll
    for (int j = 0; j < 4; ++j) {
      uint2 sa, sb;
      sa.x = f2bf(xa[j].x) | (f2bf(xa[j].y) << 16);
      sa.y = f2bf(xa[j].z) | (f2bf(xa[j].w) << 16);
      sb.x = f2bf(xb[j].x) | (f2bf(xb[j].y) << 16);
      sb.y = f2bf(xb[j].z) | (f2bf(xb[j].w) << 16);
      *(uint2*)(xbf + ((size_t)nA << 10) + (j << 8) + (lane << 2)) = sa;
      *(uint2*)(xbf + ((size_t)nB << 10) + (j << 8) + (lane << 2)) = sb;
    }

    double pA[8] = {}, pB[8] = {};
#pragma unroll
    for (int j = 0; j < 4; ++j) {
#pragma unroll
      for (int e = 0; e < 8; ++e) {
        float4 wv = *(const float4*)&wlds[e * 1024 + (j << 8) + (lane << 2)];
        pA[e] += (double)xa[j].x * (double)wv.x;
        pA[e] += (double)xa[j].y * (double)wv.y;
        pA[e] += (double)xa[j].z * (double)wv.z;
        pA[e] += (double)xa[j].w * (double)wv.w;
        pB[e] += (double)xb[j].x * (double)wv.x;
        pB[e] += (double)xb[j].y * (double)wv.y;
        pB[e] += (double)xb[j].z * (double)wv.z;
        pB[e] += (double)xb[j].w * (double)wv.w;
      }
      __builtin_amdgcn_sched_barrier(0);   // stop cross-j w-load hoisting
    }

    // f32 cross-lane reduce (two independent chains interleave)
    float qA[8], qB[8];
#pragma unroll
    for (int e = 0; e < 8; ++e) { qA[e] = (float)pA[e]; qB[e] = (float)pB[e]; }
#pragma unroll
    for (int e = 0; e < 8; ++e) {
      qA[e] += __shfl_xor(qA[e], 1);
      qB[e] += __shfl_xor(qB[e], 1);
      qA[e] += __shfl_xor(qA[e], 2);
      qB[e] += __shfl_xor(qB[e], 2);
      qA[e] += __shfl_xor(qA[e], 4);
      qB[e] += __shfl_xor(qB[e], 4);
    }
    // static select tree: s = q[ea] without runtime indexing (rule #20)
    float sA, sB;
    {
      float q0 = (ea & 1) ? qA[1] : qA[0], q1 = (ea & 1) ? qA[3] : qA[2];
      float q2 = (ea & 1) ? qA[5] : qA[4], q3 = (ea & 1) ? qA[7] : qA[6];
      float r0 = (ea & 2) ? q1 : q0, r1 = (ea & 2) ? q3 : q2;
      sA = (ea & 4) ? r1 : r0;
      q0 = (ea & 1) ? qB[1] : qB[0]; q1 = (ea & 1) ? qB[3] : qB[2];
      q2 = (ea & 1) ? qB[5] : qB[4]; q3 = (ea & 1) ? qB[7] : qB[6];
      r0 = (ea & 2) ? q1 : q0; r1 = (ea & 2) ? q3 : q2;
      sB = (ea & 4) ? r1 : r0;
    }
    sA += __shfl_xor(sA, 8);  sB += __shfl_xor(sB, 8);
    sA += __shfl_xor(sA, 16); sB += __shfl_xor(sB, 16);
    sA += __shfl_xor(sA, 32); sB += __shfl_xor(sB, 32);
    sA += bias; sB += bias;
    // argmax over experts (lane bits 0-2); first index on ties (np.argmax)
    float bvA = sA, bvB = sB;
    int biA = ea, biB = ea;
#pragma unroll
    for (int mask = 1; mask <= 4; mask <<= 1) {
      float ovA = __shfl_xor(bvA, mask), ovB = __shfl_xor(bvB, mask);
      int oiA = __shfl_xor(biA, mask), oiB = __shfl_xor(biB, mask);
      if (ovA > bvA || (ovA == bvA && oiA < biA)) { bvA = ovA; biA = oiA; }
      if (ovB > bvB || (ovB == bvB && oiB < biB)) { bvB = ovB; biB = oiB; }
    }
    if (lane == 0) {
      top[nA] = biA;
      top[nB] = biB;
    }
  }
}

// Counting sort of 16384 expert ids in ONE block (1024 threads x 16 tokens).
// Per-thread histogram packed as 2x u64 (8 experts x 16-bit fields); Hillis-
// Steele scan over packed u64s in LDS; ordered scatter into per-expert lists.
// Deterministic; lists sorted by token index (GEMM gather locality).
__global__ __launch_bounds__(1024) void k_sort(const int* __restrict__ top,
                                               int* __restrict__ counts,
                                               int* __restrict__ tok) {
  __shared__ unsigned long long sc[2][2][1024];  // 32 KB
  const int t = threadIdx.x;

  int4 v[4];
  const int4* tp = (const int4*)(top + t * 16);
#pragma unroll
  for (int i = 0; i < 4; ++i) v[i] = tp[i];

  unsigned long long h0 = 0, h1 = 0;
#pragma unroll
  for (int i = 0; i < 16; ++i) {
    int e = ((const int*)v)[i];
    if (e < 4) h0 += 1ull << (16 * e);
    else       h1 += 1ull << (16 * (e - 4));
  }
  sc[0][0][t] = h0;
  sc[0][1][t] = h1;
  __syncthreads();

  int cur = 0;
  for (int s = 1; s < 1024; s <<= 1) {
    unsigned long long a0 = sc[cur][0][t], a1 = sc[cur][1][t];
    if (t >= s) { a0 += sc[cur][0][t - s]; a1 += sc[cur][1][t - s]; }
    sc[cur ^ 1][0][t] = a0;
    sc[cur ^ 1][1][t] = a1;
    cur ^= 1;
    __syncthreads();
  }

  unsigned long long b0 = sc[cur][0][t] - h0;
  unsigned long long b1 = sc[cur][1][t] - h1;
  if (t == 1023) {
    unsigned long long i0 = sc[cur][0][t], i1 = sc[cur][1][t];
#pragma unroll
    for (int e = 0; e < 4; ++e) counts[e] = (int)((i0 >> (16 * e)) & 0xFFFF);
#pragma unroll
    for (int e = 0; e < 4; ++e) counts[4 + e] = (int)((i1 >> (16 * e)) & 0xFFFF);
  }
#pragma unroll
  for (int i = 0; i < 16; ++i) {
    int e = ((const int*)v)[i];
    int pos;
    if (e < 4) {
      pos = (int)((b0 >> (16 * e)) & 0xFFFF);
      b0 += 1ull << (16 * e);
    } else {
      int f = e - 4;
      pos = (int)((b1 >> (16 * f)) & 0xFFFF);
      b1 += 1ull << (16 * f);
    }
    tok[(e << 14) + pos] = t * 16 + i;
  }
}

// Grouped GEMM, 8-phase 256^2 template (T3+T4+T5 per the measured ladder):
// C[m,o] = sum_d Xg[m,d] * W[o,d]. BM=BN=256, BK=64, 8 waves (2Mx4N), each
// wave owns a 128x64 output (8x4 fragments of 16x16), 16 K-tiles.
// LDS: dbuf x [256][64] x {A,B} = 128 KB -> 1 block/CU. Per K-tile, 4 phases:
//   {ds_read frags  ||  stage 1 half-tile of NEXT K-tile into buf^1}
//   s_barrier; lgkmcnt(0)+sched_barrier (rule #18); setprio(1); 16 MFMA;
//   setprio(0); s_barrier.
// Tile-end: vmcnt(0) (own 8 prefetch loads, issued up to 3 phases earlier;
// nothing newer outstanding => equivalent to exact counted wait) + barrier
// (cross-wave LDS-write visibility). Proven 8-chunk XOR swizzle: phys chunk
// = logical ^ (row&7), realized on the GLOBAL source side (gload_lds dest
// linear, rule #21), identical class measured 0 conflicts (R6-R9).
// Grid 2048: e = bid&7 (XCD pinning -> W_e L2-resident), nt fastest, mt 0..63
// with early exit (live ~256 = 1/CU).
__global__ __launch_bounds__(512, 2) void k_gemm(const unsigned short* __restrict__ xbf,
                                                 const unsigned short* __restrict__ wbf,
                                                 const float* __restrict__ eb,
                                                 const int* __restrict__ counts,
                                                 const int* __restrict__ tokall,
                                                 float* __restrict__ out) {
  const int bid = blockIdx.x;          // 0..2047
  const int e = bid & 7;               // expert == XCD
  const int loc = bid >> 3;            // 0..255
  const int nt = loc & 3;              // col tile (fastest)
  const int mt = loc >> 2;             // token tile 0..63
  const int c = counts[e];
  if (mt * 256 >= c) return;
  const int tid = threadIdx.x;
  const int lane = tid & 63;
  const int w = tid >> 6;              // wave 0..7
  const int wr = w >> 2;               // 0..1 (M)
  const int wn = w & 3;                // 0..3 (N)
  const int* tok = tokall + (e << 14);
  const unsigned short* wb = wbf + ((size_t)e << 20);

  __shared__ unsigned short As[2][256 * 64];  // 2 x 32 KB
  __shared__ unsigned short Bs[2][256 * 64];  // 2 x 32 KB

  // Staging bases. Half hf (rows hf*128..+128), load s: chunk ci = s*512+tid,
  // row = hf*128 + ci>>3, phys chunk = ci&7, logical l = phys ^ (row&7).
  unsigned abase[2][2], bbase[2][2];
#pragma unroll
  for (int hf = 0; hf < 2; ++hf)
#pragma unroll
    for (int s = 0; s < 2; ++s) {
      int ci = s * 512 + tid;
      int row = hf * 128 + (ci >> 3);
      int l = (ci & 7) ^ (row & 7);
      int m = mt * 256 + row;
      int g = tok[(m < c) ? m : 0];    // pad rows replay token 0 (stores guarded)
      abase[hf][s] = (unsigned)(g * DIM + l * 8);
      bbase[hf][s] = (unsigned)((nt * 256 + row) * DIM + l * 8);
    }
  const unsigned ldst = (unsigned)((w << 6) << 3);  // wave's lds chunk base (elems)

  // ds_read offsets (elements): frag row r, k-half kh -> logical chunk
  // kh*4 + (lane>>4), phys = logical ^ (r&7), off = r*64 + phys*8.
  unsigned aoff[2][8], boff[2][4];
#pragma unroll
  for (int kh = 0; kh < 2; ++kh) {
#pragma unroll
    for (int i = 0; i < 8; ++i) {
      int r = wr * 128 + i * 16 + (lane & 15);
      int p = ((kh << 2) + (lane >> 4)) ^ (r & 7);
      aoff[kh][i] = r * 64 + p * 8;
    }
#pragma unroll
    for (int j = 0; j < 4; ++j) {
      int r = wn * 64 + j * 16 + (lane & 15);
      int p = ((kh << 2) + (lane >> 4)) ^ (r & 7);
      boff[kh][j] = r * 64 + p * 8;
    }
  }

  // stage one half-tile (2 x gload_lds/thread). mat: 0=A, 1=B.
  auto stage = [&](int buf, int mat, int hf, int k0) {
    unsigned short* lds = mat ? &Bs[buf][0] : &As[buf][0];
    const unsigned short* src = mat ? wb : xbf;
    const unsigned* base = mat ? bbase[hf] : abase[hf];
#pragma unroll
    for (int s = 0; s < 2; ++s)
      __builtin_amdgcn_global_load_lds(
          (const AS1 unsigned int*)(src + base[s] + k0),
          (AS3 unsigned int*)(lds + hf * 8192 + s * 4096 + ldst),
          16, 0, 0);
  };

  // prologue: tile 0 fully staged
  stage(0, 0, 0, 0); stage(0, 0, 1, 0); stage(0, 1, 0, 0); stage(0, 1, 1, 0);
  asm volatile("s_waitcnt vmcnt(0)" ::: "memory");
  __builtin_amdgcn_s_barrier();

  f32x4 acc[8][4] = {};
  bf16x8 af[4], bf[4];

#pragma unroll 1
  for (int kt = 0; kt < 16; ++kt) {
    const int buf = kt & 1;
    const int k0n = (kt + 1) << 6;
    const unsigned short* Ab = &As[buf][0];
    const unsigned short* Bb = &Bs[buf][0];
    const bool pre = kt < 15;

    // ---- phase 0: mg=0, kh=0 (reads B kh0 + A 0..3 kh0) ----
#pragma unroll
    for (int j = 0; j < 4; ++j) bf[j] = *(const bf16x8*)&Bb[boff[0][j]];
#pragma unroll
    for (int i = 0; i < 4; ++i) af[i] = *(const bf16x8*)&Ab[aoff[0][i]];
    if (pre) stage(buf ^ 1, 0, 0, k0n);
    __builtin_amdgcn_s_barrier();
    asm volatile("s_waitcnt lgkmcnt(0)" ::: "memory");
    __builtin_amdgcn_sched_barrier(0);
    __builtin_amdgcn_s_setprio(1);
#pragma unroll
    for (int i = 0; i < 4; ++i)
#pragma unroll
      for (int j = 0; j < 4; ++j)
        acc[i][j] = __builtin_amdgcn_mfma_f32_16x16x32_bf16(af[i], bf[j], acc[i][j], 0, 0, 0);
    __builtin_amdgcn_s_setprio(0);
    __builtin_amdgcn_s_barrier();

    // ---- phase 1: mg=1, kh=0 ----
#pragma unroll
    for (int i = 0; i < 4; ++i) af[i] = *(const bf16x8*)&Ab[aoff[0][4 + i]];
    if (pre) stage(buf ^ 1, 0, 1, k0n);
    __builtin_amdgcn_s_barrier();
    asm volatile("s_waitcnt lgkmcnt(0)" ::: "memory");
    __builtin_amdgcn_sched_barrier(0);
    __builtin_amdgcn_s_setprio(1);
#pragma unroll
    for (int i = 0; i < 4; ++i)
#pragma unroll
      for (int j = 0; j < 4; ++j)
        acc[4 + i][j] = __builtin_amdgcn_mfma_f32_16x16x32_bf16(af[i], bf[j], acc[4 + i][j], 0, 0, 0);
    __builtin_amdgcn_s_setprio(0);
    __builtin_amdgcn_s_barrier();

    // ---- phase 2: mg=0, kh=1 ----
#pragma unroll
    for (int j = 0; j < 4; ++j) bf[j] = *(const bf16x8*)&Bb[boff[1][j]];
#pragma unroll
    for (int i = 0; i < 4; ++i) af[i] = *(const bf16x8*)&Ab[aoff[1][i]];
    if (pre) stage(buf ^ 1, 1, 0, k0n);
    __builtin_amdgcn_s_barrier();
    asm volatile("s_waitcnt lgkmcnt(0)" ::: "memory");
    __builtin_amdgcn_sched_barrier(0);
    __builtin_amdgcn_s_setprio(1);
#pragma unroll
    for (int i = 0; i < 4; ++i)
#pragma unroll
      for (int j = 0; j < 4; ++j)
        acc[i][j] = __builtin_amdgcn_mfma_f32_16x16x32_bf16(af[i], bf[j], acc[i][j], 0, 0, 0);
    __builtin_amdgcn_s_setprio(0);
    __builtin_amdgcn_s_barrier();

    // ---- phase 3: mg=1, kh=1 ----
#pragma unroll
    for (int i = 0; i < 4; ++i) af[i] = *(const bf16x8*)&Ab[aoff[1][4 + i]];
    if (pre) stage(buf ^ 1, 1, 1, k0n);
    __builtin_amdgcn_s_barrier();
    asm volatile("s_waitcnt lgkmcnt(0)" ::: "memory");
    __builtin_amdgcn_sched_barrier(0);
    __builtin_amdgcn_s_setprio(1);
#pragma unroll
    for (int i = 0; i < 4; ++i)
#pragma unroll
      for (int j = 0; j < 4; ++j)
        acc[4 + i][j] = __builtin_amdgcn_mfma_f32_16x16x32_bf16(af[i], bf[j], acc[4 + i][j], 0, 0, 0);
    __builtin_amdgcn_s_setprio(0);
    // tile-end: own prefetch loads landed (issued up to 3 phases ago), then
    // barrier so ALL waves' LDS writes are visible before next ds_read.
    asm volatile("s_waitcnt vmcnt(0)" ::: "memory");
    __builtin_amdgcn_s_barrier();
  }

  // Epilogue: C/D layout col = lane&15, row = (lane>>4)*4 + reg. Bias+scatter.
  const int colb = (nt << 8) + (wn << 6) + (lane & 15);
  float bias[4];
#pragma unroll
  for (int j = 0; j < 4; ++j) bias[j] = eb[(e << 10) + colb + j * 16];
#pragma unroll
  for (int i = 0; i < 8; ++i) {
    int rbase = (mt << 8) + (wr << 7) + i * 16 + ((lane >> 4) << 2);
#pragma unroll
    for (int r = 0; r < 4; ++r) {
      int mm = rbase + r;
      if (mm < c) {
        int g = tok[mm];
        float* op = out + ((size_t)g << 10);
#pragma unroll
        for (int j = 0; j < 4; ++j) op[colb + j * 16] = acc[i][j][r] + bias[j];
      }
    }
  }
}

extern "C" void kernel_launch(void* const* d_in, const int* in_sizes, int n_in,
                              void* d_out, int out_size, void* d_ws, size_t ws_size,
                              hipStream_t stream) {
  const float* x  = (const float*)d_in[0];
  const float* rw = (const float*)d_in[1];
  const float* rb = (const float*)d_in[2];
  const float* ew = (const float*)d_in[3];
  const float* eb = (const float*)d_in[4];
  float* out = (float*)d_out;

  char* ws = (char*)d_ws;
  unsigned short* wbf = (unsigned short*)ws;                         // 16 MB
  unsigned short* xbf = (unsigned short*)(ws + (16u << 20));         // 32 MB
  int* tok    = (int*)(ws + (48u << 20));                            // 512 KB
  int* counts = (int*)(ws + (48u << 20) + (1u << 19));               // 32 B
  int* top    = (int*)(ws + (48u << 20) + (1u << 19) + 128);         // 64 KB

  k_convw<<<4096, 256, 0, stream>>>(ew, wbf);
  k_router<<<NTOK / 16, 256, 0, stream>>>(x, rw, rb, xbf, top);      // 1024 blocks
  k_sort<<<1, 1024, 0, stream>>>(top, counts, tok);
  k_gemm<<<2048, 512, 0, stream>>>(xbf, wbf, eb, counts, tok, out);
}

// Round 13
// 114.248 us; speedup vs baseline: 1.0461x; 1.0461x over previous
//
#include <hip/hip_runtime.h>
#include <hip/hip_bf16.h>

// MoE top-1: N=16384 tokens, D=1024, E=8 experts.
// out[n] = expert_w[argmax(router(x[n]))] @ x[n] + expert_b[e]
//
// Pipeline: router (rw in LDS, token-pair ILP, f64 in-lane dots, fused
// x->bf16) -> k_sortconv (block 0: counting sort; blocks 1..1024: W->bf16,
// overlapped) -> grouped bf16-MFMA GEMM (256^2, 8 waves, 4 phases/K-tile with
// K-SPLIT half-tiles so each phase depends on ONE prefetched half-pair ->
// counted vmcnt(4), never 0 in-loop; row-pair-line LDS layout, proven
// 0-conflict XOR swizzle; flat grid, no XCD pinning).

#define NTOK 16384
#define DIM  1024
#define NEXP 8

#define AS1 __attribute__((address_space(1)))
#define AS3 __attribute__((address_space(3)))

typedef __bf16 bf16x8 __attribute__((ext_vector_type(8)));
typedef float  f32x4  __attribute__((ext_vector_type(4)));

__device__ __forceinline__ unsigned int f2bf(float f) {
  unsigned int u = __builtin_bit_cast(unsigned int, f);
  u += 0x7FFFu + ((u >> 16) & 1u);   // round-to-nearest-even (finite inputs)
  return u >> 16;
}

// Router: rw (32 KB) staged in LDS once per block. Lane l owns x elements
// {j*256 + 4l .. +4}, j=0..3 (16 B/lane stride => conflict-free ds_read_b128).
// TWO tokens per w-fragment read. j-OUTER / e-INNER with a sched_barrier(0)
// after each j caps live w-fragments (~8 VGPRs). In-lane partials in f64
// (f32 products exact => argmax ground-truth); cross-lane reduce in f32
// (err ~3e-7 << np's own f32 noise). Fused x->bf16. No atomics.
__global__ __launch_bounds__(256) void k_router(const float* __restrict__ x,
                                                const float* __restrict__ rw,
                                                const float* __restrict__ rb,
                                                unsigned short* __restrict__ xbf,
                                                int* __restrict__ top) {
  __shared__ float wlds[NEXP * DIM];   // 32 KB
  const int tid = threadIdx.x;
  const int lane = tid & 63;
  const int wave = tid >> 6;
#pragma unroll
  for (int i = 0; i < 8; ++i)
    ((float4*)wlds)[tid + 256 * i] = ((const float4*)rw)[tid + 256 * i];
  __syncthreads();

  const int ea = lane & 7;
  const float bias = rb[ea];

#pragma unroll 1
  for (int tp = 0; tp < 2; ++tp) {     // two token-pairs per wave (4 tokens)
    const int nA = (blockIdx.x << 4) + (wave << 2) + (tp << 1);
    const int nB = nA + 1;

    float4 xa[4], xb[4];
#pragma unroll
    for (int j = 0; j < 4; ++j) {      // 8 independent 16B loads (deep MLP)
      xa[j] = *(const float4*)(x + ((size_t)nA << 10) + (j << 8) + (lane << 2));
      xb[j] = *(const float4*)(x + ((size_t)nB << 10) + (j << 8) + (lane << 2));
    }

    // fused bf16 conversion + store: 8 B/lane per (token,j), coalesced 512 B
#pragma unroll
    for (int j = 0; j < 4; ++j) {
      uint2 sa, sb;
      sa.x = f2bf(xa[j].x) | (f2bf(xa[j].y) << 16);
      sa.y = f2bf(xa[j].z) | (f2bf(xa[j].w) << 16);
      sb.x = f2bf(xb[j].x) | (f2bf(xb[j].y) << 16);
      sb.y = f2bf(xb[j].z) | (f2bf(xb[j].w) << 16);
      *(uint2*)(xbf + ((size_t)nA << 10) + (j << 8) + (lane << 2)) = sa;
      *(uint2*)(xbf + ((size_t)nB << 10) + (j << 8) + (lane << 2)) = sb;
    }

    double pA[8] = {}, pB[8] = {};
#pragma unroll
    for (int j = 0; j < 4; ++j) {
#pragma unroll
      for (int e = 0; e < 8; ++e) {
        float4 wv = *(const float4*)&wlds[e * 1024 + (j << 8) + (lane << 2)];
        pA[e] += (double)xa[j].x * (double)wv.x;
        pA[e] += (double)xa[j].y * (double)wv.y;
        pA[e] += (double)xa[j].z * (double)wv.z;
        pA[e] += (double)xa[j].w * (double)wv.w;
        pB[e] += (double)xb[j].x * (double)wv.x;
        pB[e] += (double)xb[j].y * (double)wv.y;
        pB[e] += (double)xb[j].z * (double)wv.z;
        pB[e] += (double)xb[j].w * (double)wv.w;
      }
      __builtin_amdgcn_sched_barrier(0);   // stop cross-j w-load hoisting
    }

    // f32 cross-lane reduce (two independent chains interleave)
    float qA[8], qB[8];
#pragma unroll
    for (int e = 0; e < 8; ++e) { qA[e] = (float)pA[e]; qB[e] = (float)pB[e]; }
#pragma unroll
    for (int e = 0; e < 8; ++e) {
      qA[e] += __shfl_xor(qA[e], 1);
      qB[e] += __shfl_xor(qB[e], 1);
      qA[e] += __shfl_xor(qA[e], 2);
      qB[e] += __shfl_xor(qB[e], 2);
      qA[e] += __shfl_xor(qA[e], 4);
      qB[e] += __shfl_xor(qB[e], 4);
    }
    // static select tree: s = q[ea] without runtime indexing (rule #20)
    float sA, sB;
    {
      float q0 = (ea & 1) ? qA[1] : qA[0], q1 = (ea & 1) ? qA[3] : qA[2];
      float q2 = (ea & 1) ? qA[5] : qA[4], q3 = (ea & 1) ? qA[7] : qA[6];
      float r0 = (ea & 2) ? q1 : q0, r1 = (ea & 2) ? q3 : q2;
      sA = (ea & 4) ? r1 : r0;
      q0 = (ea & 1) ? qB[1] : qB[0]; q1 = (ea & 1) ? qB[3] : qB[2];
      q2 = (ea & 1) ? qB[5] : qB[4]; q3 = (ea & 1) ? qB[7] : qB[6];
      r0 = (ea & 2) ? q1 : q0; r1 = (ea & 2) ? q3 : q2;
      sB = (ea & 4) ? r1 : r0;
    }
    sA += __shfl_xor(sA, 8);  sB += __shfl_xor(sB, 8);
    sA += __shfl_xor(sA, 16); sB += __shfl_xor(sB, 16);
    sA += __shfl_xor(sA, 32); sB += __shfl_xor(sB, 32);
    sA += bias; sB += bias;
    // argmax over experts (lane bits 0-2); first index on ties (np.argmax)
    float bvA = sA, bvB = sB;
    int biA = ea, biB = ea;
#pragma unroll
    for (int mask = 1; mask <= 4; mask <<= 1) {
      float ovA = __shfl_xor(bvA, mask), ovB = __shfl_xor(bvB, mask);
      int oiA = __shfl_xor(biA, mask), oiB = __shfl_xor(biB, mask);
      if (ovA > bvA || (ovA == bvA && oiA < biA)) { bvA = ovA; biA = oiA; }
      if (ovB > bvB || (ovB == bvB && oiB < biB)) { bvB = ovB; biB = oiB; }
    }
    if (lane == 0) {
      top[nA] = biA;
      top[nB] = biB;
    }
  }
}

// Merged: block 0 = counting sort of 16384 expert ids (1024 thr x 16 tokens,
// packed-u64 histogram + Hillis-Steele scan, deterministic, token-sorted
// lists); blocks 1..1024 = expert_w f32->bf16 (8 elems/thread) running on the
// other CUs in parallel with the single-CU sort.
__global__ __launch_bounds__(1024) void k_sortconv(const float* __restrict__ ew,
                                                   unsigned short* __restrict__ wbf,
                                                   const int* __restrict__ top,
                                                   int* __restrict__ counts,
                                                   int* __restrict__ tok) {
  const int t = threadIdx.x;
  if (blockIdx.x > 0) {                 // ---- convw part ----
    size_t i = ((size_t)(blockIdx.x - 1) * 1024 + t) * 8;
    const float4* p = (const float4*)(ew + i);
    float4 a = p[0], b = p[1];
    unsigned int w0 = f2bf(a.x) | (f2bf(a.y) << 16);
    unsigned int w1 = f2bf(a.z) | (f2bf(a.w) << 16);
    unsigned int w2 = f2bf(b.x) | (f2bf(b.y) << 16);
    unsigned int w3 = f2bf(b.z) | (f2bf(b.w) << 16);
    *(uint4*)(wbf + i) = make_uint4(w0, w1, w2, w3);
    return;
  }

  // ---- sort part (block 0) ----
  __shared__ unsigned long long sc[2][2][1024];  // 32 KB
  int4 v[4];
  const int4* tp = (const int4*)(top + t * 16);
#pragma unroll
  for (int i = 0; i < 4; ++i) v[i] = tp[i];

  unsigned long long h0 = 0, h1 = 0;
#pragma unroll
  for (int i = 0; i < 16; ++i) {
    int e = ((const int*)v)[i];
    if (e < 4) h0 += 1ull << (16 * e);
    else       h1 += 1ull << (16 * (e - 4));
  }
  sc[0][0][t] = h0;
  sc[0][1][t] = h1;
  __syncthreads();

  int cur = 0;
  for (int s = 1; s < 1024; s <<= 1) {
    unsigned long long a0 = sc[cur][0][t], a1 = sc[cur][1][t];
    if (t >= s) { a0 += sc[cur][0][t - s]; a1 += sc[cur][1][t - s]; }
    sc[cur ^ 1][0][t] = a0;
    sc[cur ^ 1][1][t] = a1;
    cur ^= 1;
    __syncthreads();
  }

  unsigned long long b0 = sc[cur][0][t] - h0;
  unsigned long long b1 = sc[cur][1][t] - h1;
  if (t == 1023) {
    unsigned long long i0 = sc[cur][0][t], i1 = sc[cur][1][t];
#pragma unroll
    for (int e = 0; e < 4; ++e) counts[e] = (int)((i0 >> (16 * e)) & 0xFFFF);
#pragma unroll
    for (int e = 0; e < 4; ++e) counts[4 + e] = (int)((i1 >> (16 * e)) & 0xFFFF);
  }
#pragma unroll
  for (int i = 0; i < 16; ++i) {
    int e = ((const int*)v)[i];
    int pos;
    if (e < 4) {
      pos = (int)((b0 >> (16 * e)) & 0xFFFF);
      b0 += 1ull << (16 * e);
    } else {
      int f = e - 4;
      pos = (int)((b1 >> (16 * f)) & 0xFFFF);
      b1 += 1ull << (16 * f);
    }
    tok[(e << 14) + pos] = t * 16 + i;
  }
}

// Grouped GEMM, 256^2 / 8 waves / BK=64, 4 phases per K-tile with COUNTED
// vmcnt (the R12 fix): half-tiles are split BY K (Ak0 = all 256 rows, k0..31)
// so phase (mg,kh) depends only on sub-buffers (A,kh),(B,kh) — uniform across
// waves. Stage order per tile: Ak0,Bk0,Ak1,Bk1 (2 loads/wave each);
// vmcnt(4) at ends of phases 1 and 3 waits for exactly the oldest half-pair
// (never drains to 0 in-loop; cover ~2-3 phases ≈ 550-800 cyc). Sub-buffer
// layout = R11's row-pair lines ([128 lines][64 elems], line L = rows 2L,2L+1
// of a 32-k half; phys chunk = logical ^ (L&7)) — measured ZERO bank
// conflicts. gload_lds dest linear; swizzle realized on the global source
// (rule #21). Flat grid 2048 (e = tau>>8): no expert->XCD pinning, so expert
// count imbalance spreads across all XCDs (R12's pinning made it a tail).
__global__ __launch_bounds__(512, 2) void k_gemm(const unsigned short* __restrict__ xbf,
                                                 const unsigned short* __restrict__ wbf,
                                                 const float* __restrict__ eb,
                                                 const int* __restrict__ counts,
                                                 const int* __restrict__ tokall,
                                                 float* __restrict__ out) {
  const int tau = blockIdx.x;          // 0..2047
  const int e = tau >> 8;              // expert
  const int mt = (tau >> 2) & 63;      // token tile
  const int nt = tau & 3;              // col tile
  const int c = counts[e];
  if (mt * 256 >= c) return;
  const int tid = threadIdx.x;
  const int lane = tid & 63;
  const int w = tid >> 6;              // wave 0..7
  const int wr = w >> 2;               // 0..1 (M)
  const int wn = w & 3;                // 0..3 (N)
  const int* tok = tokall + (e << 14);
  const unsigned short* wb = wbf + ((size_t)e << 20);

  __shared__ unsigned short As[2][2][8192];  // [buf][kh][128 lines x 64 elems]
  __shared__ unsigned short Bs[2][2][8192];  // total 128 KB

  // Staging bases. Sub-buffer (kh=h): chunk ci = s*512 + tid -> line L=ci>>3,
  // phys chunk P=ci&7; logical c = P ^ (L&7); row r = 2L + (c>>2);
  // k-offset = h*32 + (c&3)*8.
  unsigned abase[2][2], bbase[2][2];   // [h][s]
#pragma unroll
  for (int h = 0; h < 2; ++h)
#pragma unroll
    for (int s = 0; s < 2; ++s) {
      int ci = s * 512 + tid;
      int L = ci >> 3;
      int cc = (ci & 7) ^ (L & 7);
      int r = 2 * L + (cc >> 2);
      int kof = h * 32 + (cc & 3) * 8;
      int m = mt * 256 + r;
      int g = tok[(m < c) ? m : 0];    // pad rows replay token 0 (stores guarded)
      abase[h][s] = (unsigned)(g * DIM + kof);
      bbase[h][s] = (unsigned)((nt * 256 + r) * DIM + kof);
    }
  const unsigned ldst = (unsigned)(w * 512);  // wave's linear dest base (elems)

  // ds_read offsets within a kh sub-buffer (same for both kh): frag row r,
  // k-quarter q = lane>>4 -> logical chunk (r&1)*4 + q, phys = ^(L&7).
  unsigned aoff[8], boff[4];
#pragma unroll
  for (int i = 0; i < 8; ++i) {
    int r = wr * 128 + i * 16 + (lane & 15);
    int L = r >> 1;
    int p = (((r & 1) << 2) + (lane >> 4)) ^ (L & 7);
    aoff[i] = L * 64 + p * 8;
  }
#pragma unroll
  for (int j = 0; j < 4; ++j) {
    int r = wn * 64 + j * 16 + (lane & 15);
    int L = r >> 1;
    int p = (((r & 1) << 2) + (lane >> 4)) ^ (L & 7);
    boff[j] = L * 64 + p * 8;
  }

  // stage one K-split half (2 gload_lds/thread). mat: 0=A, 1=B; h: kh.
  auto stage = [&](int buf, int mat, int h, int k0) {
    unsigned short* lds = mat ? &Bs[buf][h][0] : &As[buf][h][0];
    const unsigned short* src = mat ? wb : xbf;
    const unsigned* base = mat ? bbase[h] : abase[h];
#pragma unroll
    for (int s = 0; s < 2; ++s)
      __builtin_amdgcn_global_load_lds(
          (const AS1 unsigned int*)(src + base[s] + k0),
          (AS3 unsigned int*)(lds + s * 4096 + ldst),
          16, 0, 0);
  };

  // prologue: tile 0, order Ak0,Bk0,Ak1,Bk1; wait for the kh0 pair only.
  stage(0, 0, 0, 0); stage(0, 1, 0, 0); stage(0, 0, 1, 0); stage(0, 1, 1, 0);
  asm volatile("s_waitcnt vmcnt(4)" ::: "memory");
  __builtin_amdgcn_s_barrier();

  f32x4 acc[8][4] = {};
  bf16x8 af[4], bf[4];

#pragma unroll 1
  for (int kt = 0; kt < 16; ++kt) {
    const int buf = kt & 1;
    const int k0n = (kt + 1) << 6;
    const bool pre = kt < 15;

    // ---- phase 0: mg=0, kh=0 ----
#pragma unroll
    for (int j = 0; j < 4; ++j) bf[j] = *(const bf16x8*)&Bs[buf][0][boff[j]];
#pragma unroll
    for (int i = 0; i < 4; ++i) af[i] = *(const bf16x8*)&As[buf][0][aoff[i]];
    if (pre) stage(buf ^ 1, 0, 0, k0n);                 // Ak0(kt+1)
    __builtin_amdgcn_s_barrier();
    asm volatile("s_waitcnt lgkmcnt(0)" ::: "memory");
    __builtin_amdgcn_sched_barrier(0);
    __builtin_amdgcn_s_setprio(1);
#pragma unroll
    for (int i = 0; i < 4; ++i)
#pragma unroll
      for (int j = 0; j < 4; ++j)
        acc[i][j] = __builtin_amdgcn_mfma_f32_16x16x32_bf16(af[i], bf[j], acc[i][j], 0, 0, 0);
    __builtin_amdgcn_s_setprio(0);
    __builtin_amdgcn_s_barrier();

    // ---- phase 1: mg=1, kh=0 ----
#pragma unroll
    for (int i = 0; i < 4; ++i) af[i] = *(const bf16x8*)&As[buf][0][aoff[4 + i]];
    if (pre) stage(buf ^ 1, 1, 0, k0n);                 // Bk0(kt+1)
    __builtin_amdgcn_s_barrier();
    asm volatile("s_waitcnt lgkmcnt(0)" ::: "memory");
    __builtin_amdgcn_sched_barrier(0);
    __builtin_amdgcn_s_setprio(1);
#pragma unroll
    for (int i = 0; i < 4; ++i)
#pragma unroll
      for (int j = 0; j < 4; ++j)
        acc[4 + i][j] = __builtin_amdgcn_mfma_f32_16x16x32_bf16(af[i], bf[j], acc[4 + i][j], 0, 0, 0);
    __builtin_amdgcn_s_setprio(0);
    // counted wait: oldest 4 = Ak1,Bk1 of THIS tile (needed by phase 2).
    if (pre) asm volatile("s_waitcnt vmcnt(4)" ::: "memory");
    else     asm volatile("s_waitcnt vmcnt(0)" ::: "memory");
    __builtin_amdgcn_s_barrier();

    // ---- phase 2: mg=0, kh=1 ----
#pragma unroll
    for (int j = 0; j < 4; ++j) bf[j] = *(const bf16x8*)&Bs[buf][1][boff[j]];
#pragma unroll
    for (int i = 0; i < 4; ++i) af[i] = *(const bf16x8*)&As[buf][1][aoff[i]];
    if (pre) stage(buf ^ 1, 0, 1, k0n);                 // Ak1(kt+1)
    __builtin_amdgcn_s_barrier();
    asm volatile("s_waitcnt lgkmcnt(0)" ::: "memory");
    __builtin_amdgcn_sched_barrier(0);
    __builtin_amdgcn_s_setprio(1);
#pragma unroll
    for (int i = 0; i < 4; ++i)
#pragma unroll
      for (int j = 0; j < 4; ++j)
        acc[i][j] = __builtin_amdgcn_mfma_f32_16x16x32_bf16(af[i], bf[j], acc[i][j], 0, 0, 0);
    __builtin_amdgcn_s_setprio(0);
    __builtin_amdgcn_s_barrier();

    // ---- phase 3: mg=1, kh=1 ----
#pragma unroll
    for (int i = 0; i < 4; ++i) af[i] = *(const bf16x8*)&As[buf][1][aoff[4 + i]];
    if (pre) stage(buf ^ 1, 1, 1, k0n);                 // Bk1(kt+1)
    __builtin_amdgcn_s_barrier();
    asm volatile("s_waitcnt lgkmcnt(0)" ::: "memory");
    __builtin_amdgcn_sched_barrier(0);
    __builtin_amdgcn_s_setprio(1);
#pragma unroll
    for (int i = 0; i < 4; ++i)
#pragma unroll
      for (int j = 0; j < 4; ++j)
        acc[4 + i][j] = __builtin_amdgcn_mfma_f32_16x16x32_bf16(af[i], bf[j], acc[4 + i][j], 0, 0, 0);
    __builtin_amdgcn_s_setprio(0);
    // counted wait: oldest 4 = Ak0,Bk0 of tile kt+1 (needed by next phase 0).
    if (pre) asm volatile("s_waitcnt vmcnt(4)" ::: "memory");
    __builtin_amdgcn_s_barrier();
  }

  // Epilogue: C/D layout col = lane&15, row = (lane>>4)*4 + reg. Bias+scatter.
  const int colb = (nt << 8) + (wn << 6) + (lane & 15);
  float bias[4];
#pragma unroll
  for (int j = 0; j < 4; ++j) bias[j] = eb[(e << 10) + colb + j * 16];
#pragma unroll
  for (int i = 0; i < 8; ++i) {
    int rbase = (mt << 8) + (wr << 7) + i * 16 + ((lane >> 4) << 2);
#pragma unroll
    for (int r = 0; r < 4; ++r) {
      int mm = rbase + r;
      if (mm < c) {
        int g = tok[mm];
        float* op = out + ((size_t)g << 10);
#pragma unroll
        for (int j = 0; j < 4; ++j) op[colb + j * 16] = acc[i][j][r] + bias[j];
      }
    }
  }
}

extern "C" void kernel_launch(void* const* d_in, const int* in_sizes, int n_in,
                              void* d_out, int out_size, void* d_ws, size_t ws_size,
                              hipStream_t stream) {
  const float* x  = (const float*)d_in[0];
  const float* rw = (const float*)d_in[1];
  const float* rb = (const float*)d_in[2];
  const float* ew = (const float*)d_in[3];
  const float* eb = (const float*)d_in[4];
  float* out = (float*)d_out;

  char* ws = (char*)d_ws;
  unsigned short* wbf = (unsigned short*)ws;                         // 16 MB
  unsigned short* xbf = (unsigned short*)(ws + (16u << 20));         // 32 MB
  int* tok    = (int*)(ws + (48u << 20));                            // 512 KB
  int* counts = (int*)(ws + (48u << 20) + (1u << 19));               // 32 B
  int* top    = (int*)(ws + (48u << 20) + (1u << 19) + 128);         // 64 KB

  k_router<<<NTOK / 16, 256, 0, stream>>>(x, rw, rb, xbf, top);      // 1024 blocks
  k_sortconv<<<1025, 1024, 0, stream>>>(ew, wbf, top, counts, tok);  // sort || convw
  k_gemm<<<2048, 512, 0, stream>>>(xbf, wbf, eb, counts, tok, out);
}

// Round 14
// 100.756 us; speedup vs baseline: 1.1861x; 1.1339x over previous
//
#include <hip/hip_runtime.h>
#include <hip/hip_bf16.h>

// MoE top-1: N=16384 tokens, D=1024, E=8 experts.
// out[n] = expert_w[argmax(router(x[n]))] @ x[n] + expert_b[e]
//
// Pipeline: router (rw in LDS, token-pair ILP, f64 in-lane dots, fused
// x->bf16) -> k_sortconv (block 0: counting sort; blocks 1..1024: W->bf16,
// overlapped) -> grouped bf16-MFMA GEMM (R9-measured-best: 128^2 tile, BK=64,
// 64 KB dbuf = 2 blocks/CU, counted vmcnt(8), raw s_barrier, expert->XCD
// pinning; 64.4 us / FETCH 36 MB / 0 bank conflicts measured).

#define NTOK 16384
#define DIM  1024
#define NEXP 8

#define AS1 __attribute__((address_space(1)))
#define AS3 __attribute__((address_space(3)))

typedef __bf16 bf16x8 __attribute__((ext_vector_type(8)));
typedef float  f32x4  __attribute__((ext_vector_type(4)));

__device__ __forceinline__ unsigned int f2bf(float f) {
  unsigned int u = __builtin_bit_cast(unsigned int, f);
  u += 0x7FFFu + ((u >> 16) & 1u);   // round-to-nearest-even (finite inputs)
  return u >> 16;
}

// Router: rw (32 KB) staged in LDS once per block. Lane l owns x elements
// {j*256 + 4l .. +4}, j=0..3 (16 B/lane stride => conflict-free ds_read_b128).
// TWO tokens per w-fragment read. j-OUTER / e-INNER with a sched_barrier(0)
// after each j caps live w-fragments (~8 VGPRs). In-lane partials in f64
// (f32 products exact => argmax ground-truth); cross-lane reduce in f32
// (err ~3e-7 << np's own f32 noise). Fused x->bf16. No atomics.
__global__ __launch_bounds__(256) void k_router(const float* __restrict__ x,
                                                const float* __restrict__ rw,
                                                const float* __restrict__ rb,
                                                unsigned short* __restrict__ xbf,
                                                int* __restrict__ top) {
  __shared__ float wlds[NEXP * DIM];   // 32 KB
  const int tid = threadIdx.x;
  const int lane = tid & 63;
  const int wave = tid >> 6;
#pragma unroll
  for (int i = 0; i < 8; ++i)
    ((float4*)wlds)[tid + 256 * i] = ((const float4*)rw)[tid + 256 * i];
  __syncthreads();

  const int ea = lane & 7;
  const float bias = rb[ea];

#pragma unroll 1
  for (int tp = 0; tp < 2; ++tp) {     // two token-pairs per wave (4 tokens)
    const int nA = (blockIdx.x << 4) + (wave << 2) + (tp << 1);
    const int nB = nA + 1;

    float4 xa[4], xb[4];
#pragma unroll
    for (int j = 0; j < 4; ++j) {      // 8 independent 16B loads (deep MLP)
      xa[j] = *(const float4*)(x + ((size_t)nA << 10) + (j << 8) + (lane << 2));
      xb[j] = *(const float4*)(x + ((size_t)nB << 10) + (j << 8) + (lane << 2));
    }

    // fused bf16 conversion + store: 8 B/lane per (token,j), coalesced 512 B
#pragma unroll
    for (int j = 0; j < 4; ++j) {
      uint2 sa, sb;
      sa.x = f2bf(xa[j].x) | (f2bf(xa[j].y) << 16);
      sa.y = f2bf(xa[j].z) | (f2bf(xa[j].w) << 16);
      sb.x = f2bf(xb[j].x) | (f2bf(xb[j].y) << 16);
      sb.y = f2bf(xb[j].z) | (f2bf(xb[j].w) << 16);
      *(uint2*)(xbf + ((size_t)nA << 10) + (j << 8) + (lane << 2)) = sa;
      *(uint2*)(xbf + ((size_t)nB << 10) + (j << 8) + (lane << 2)) = sb;
    }

    double pA[8] = {}, pB[8] = {};
#pragma unroll
    for (int j = 0; j < 4; ++j) {
#pragma unroll
      for (int e = 0; e < 8; ++e) {
        float4 wv = *(const float4*)&wlds[e * 1024 + (j << 8) + (lane << 2)];
        pA[e] += (double)xa[j].x * (double)wv.x;
        pA[e] += (double)xa[j].y * (double)wv.y;
        pA[e] += (double)xa[j].z * (double)wv.z;
        pA[e] += (double)xa[j].w * (double)wv.w;
        pB[e] += (double)xb[j].x * (double)wv.x;
        pB[e] += (double)xb[j].y * (double)wv.y;
        pB[e] += (double)xb[j].z * (double)wv.z;
        pB[e] += (double)xb[j].w * (double)wv.w;
      }
      __builtin_amdgcn_sched_barrier(0);   // stop cross-j w-load hoisting
    }

    // f32 cross-lane reduce (two independent chains interleave)
    float qA[8], qB[8];
#pragma unroll
    for (int e = 0; e < 8; ++e) { qA[e] = (float)pA[e]; qB[e] = (float)pB[e]; }
#pragma unroll
    for (int e = 0; e < 8; ++e) {
      qA[e] += __shfl_xor(qA[e], 1);
      qB[e] += __shfl_xor(qB[e], 1);
      qA[e] += __shfl_xor(qA[e], 2);
      qB[e] += __shfl_xor(qB[e], 2);
      qA[e] += __shfl_xor(qA[e], 4);
      qB[e] += __shfl_xor(qB[e], 4);
    }
    // static select tree: s = q[ea] without runtime indexing (rule #20)
    float sA, sB;
    {
      float q0 = (ea & 1) ? qA[1] : qA[0], q1 = (ea & 1) ? qA[3] : qA[2];
      float q2 = (ea & 1) ? qA[5] : qA[4], q3 = (ea & 1) ? qA[7] : qA[6];
      float r0 = (ea & 2) ? q1 : q0, r1 = (ea & 2) ? q3 : q2;
      sA = (ea & 4) ? r1 : r0;
      q0 = (ea & 1) ? qB[1] : qB[0]; q1 = (ea & 1) ? qB[3] : qB[2];
      q2 = (ea & 1) ? qB[5] : qB[4]; q3 = (ea & 1) ? qB[7] : qB[6];
      r0 = (ea & 2) ? q1 : q0; r1 = (ea & 2) ? q3 : q2;
      sB = (ea & 4) ? r1 : r0;
    }
    sA += __shfl_xor(sA, 8);  sB += __shfl_xor(sB, 8);
    sA += __shfl_xor(sA, 16); sB += __shfl_xor(sB, 16);
    sA += __shfl_xor(sA, 32); sB += __shfl_xor(sB, 32);
    sA += bias; sB += bias;
    // argmax over experts (lane bits 0-2); first index on ties (np.argmax)
    float bvA = sA, bvB = sB;
    int biA = ea, biB = ea;
#pragma unroll
    for (int mask = 1; mask <= 4; mask <<= 1) {
      float ovA = __shfl_xor(bvA, mask), ovB = __shfl_xor(bvB, mask);
      int oiA = __shfl_xor(biA, mask), oiB = __shfl_xor(biB, mask);
      if (ovA > bvA || (ovA == bvA && oiA < biA)) { bvA = ovA; biA = oiA; }
      if (ovB > bvB || (ovB == bvB && oiB < biB)) { bvB = ovB; biB = oiB; }
    }
    if (lane == 0) {
      top[nA] = biA;
      top[nB] = biB;
    }
  }
}

// Merged: block 0 = counting sort of 16384 expert ids (1024 thr x 16 tokens,
// packed-u64 histogram + Hillis-Steele scan, deterministic, token-sorted
// lists); blocks 1..1024 = expert_w f32->bf16 (8 elems/thread) running on the
// other CUs in parallel with the single-CU sort.
__global__ __launch_bounds__(1024) void k_sortconv(const float* __restrict__ ew,
                                                   unsigned short* __restrict__ wbf,
                                                   const int* __restrict__ top,
                                                   int* __restrict__ counts,
                                                   int* __restrict__ tok) {
  const int t = threadIdx.x;
  if (blockIdx.x > 0) {                 // ---- convw part ----
    size_t i = ((size_t)(blockIdx.x - 1) * 1024 + t) * 8;
    const float4* p = (const float4*)(ew + i);
    float4 a = p[0], b = p[1];
    unsigned int w0 = f2bf(a.x) | (f2bf(a.y) << 16);
    unsigned int w1 = f2bf(a.z) | (f2bf(a.w) << 16);
    unsigned int w2 = f2bf(b.x) | (f2bf(b.y) << 16);
    unsigned int w3 = f2bf(b.z) | (f2bf(b.w) << 16);
    *(uint4*)(wbf + i) = make_uint4(w0, w1, w2, w3);
    return;
  }

  // ---- sort part (block 0) ----
  __shared__ unsigned long long sc[2][2][1024];  // 32 KB
  int4 v[4];
  const int4* tp = (const int4*)(top + t * 16);
#pragma unroll
  for (int i = 0; i < 4; ++i) v[i] = tp[i];

  unsigned long long h0 = 0, h1 = 0;
#pragma unroll
  for (int i = 0; i < 16; ++i) {
    int e = ((const int*)v)[i];
    if (e < 4) h0 += 1ull << (16 * e);
    else       h1 += 1ull << (16 * (e - 4));
  }
  sc[0][0][t] = h0;
  sc[0][1][t] = h1;
  __syncthreads();

  int cur = 0;
  for (int s = 1; s < 1024; s <<= 1) {
    unsigned long long a0 = sc[cur][0][t], a1 = sc[cur][1][t];
    if (t >= s) { a0 += sc[cur][0][t - s]; a1 += sc[cur][1][t - s]; }
    sc[cur ^ 1][0][t] = a0;
    sc[cur ^ 1][1][t] = a1;
    cur ^= 1;
    __syncthreads();
  }

  unsigned long long b0 = sc[cur][0][t] - h0;
  unsigned long long b1 = sc[cur][1][t] - h1;
  if (t == 1023) {
    unsigned long long i0 = sc[cur][0][t], i1 = sc[cur][1][t];
#pragma unroll
    for (int e = 0; e < 4; ++e) counts[e] = (int)((i0 >> (16 * e)) & 0xFFFF);
#pragma unroll
    for (int e = 0; e < 4; ++e) counts[4 + e] = (int)((i1 >> (16 * e)) & 0xFFFF);
  }
#pragma unroll
  for (int i = 0; i < 16; ++i) {
    int e = ((const int*)v)[i];
    int pos;
    if (e < 4) {
      pos = (int)((b0 >> (16 * e)) & 0xFFFF);
      b0 += 1ull << (16 * e);
    } else {
      int f = e - 4;
      pos = (int)((b1 >> (16 * f)) & 0xFFFF);
      b1 += 1ull << (16 * f);
    }
    tok[(e << 14) + pos] = t * 16 + i;
  }
}

// Grouped GEMM — R9-measured-best structure, reverted verbatim:
// C[m,o] = sum_d Xg[m,d] * W[o,d]. 128x128 tile, BK=64, 4 waves,
// mfma_f32_16x16x32_bf16. Double-buffered LDS staging (2x32 KB -> 2 blocks/CU)
// with counted vmcnt(8) and raw s_barrier (no vmcnt(0) drain in-loop).
// 1D grid 8192: xcd = bid&7 = expert (W_e stays L2-resident); col-tile varies
// fastest within an XCD. Measured: 64.4 us, MfmaUtil 21.6%, FETCH 36 MB,
// SQ_LDS_BANK_CONFLICT 0.
__global__ __launch_bounds__(256, 2) void k_gemm(const unsigned short* __restrict__ xbf,
                                                 const unsigned short* __restrict__ wbf,
                                                 const float* __restrict__ eb,
                                                 const int* __restrict__ counts,
                                                 const int* __restrict__ tokall,
                                                 float* __restrict__ out) {
  const int bid = blockIdx.x;          // 0..8191
  const int e = bid & 7;               // expert == XCD (dispatch round-robins %8)
  const int loc = bid >> 3;            // 0..1023 within XCD
  const int cb = loc & 7;              // col tile (fastest -> temporal locality)
  const int t = loc >> 3;              // token tile 0..127
  const int c = counts[e];
  if (t * 128 >= c) return;
  const int n0 = cb << 7;
  const int* tok = tokall + (e << 14);
  const int tid = threadIdx.x;
  const int lane = tid & 63;
  const int wave = tid >> 6;

  __shared__ unsigned short As[2][128 * 64];  // 2 x 16 KB, chunk-swizzled
  __shared__ unsigned short Bs[2][128 * 64];

  // Staging addresses: 4 x (32 rows x 8 chunks of 16B) per buffer. LDS dest is
  // linear (global_load_lds requirement); swizzle on the GLOBAL source side:
  // physical chunk p at row r holds logical chunk p ^ (r & 7).
  const int prow = tid >> 3;
  const int pchk = tid & 7;
  size_t asrc[4], bsrc[4];
  const unsigned short* wb = wbf + ((size_t)e << 20);
#pragma unroll
  for (int s = 0; s < 4; ++s) {
    int row = s * 32 + prow;
    int m = t * 128 + row;
    int g = tok[(m < c) ? m : 0];          // pad rows replay token 0 (stores guarded)
    int l = pchk ^ (row & 7);
    asrc[s] = (size_t)g * DIM + (size_t)l * 8;
    bsrc[s] = (size_t)(n0 + row) * DIM + (size_t)l * 8;
  }

  f32x4 acc[4][4] = {};
  const int wr = wave >> 1, wc = wave & 1;

  // LDS read offsets (elements). A-frag: lane holds A[row = lane&15][k = (lane>>4)*8 + j].
  int aoff[2][4], boff[2][4];
#pragma unroll
  for (int h = 0; h < 2; ++h)
#pragma unroll
    for (int m = 0; m < 4; ++m) {
      int row = wr * 64 + m * 16 + (lane & 15);
      int p = (h * 4 + (lane >> 4)) ^ (row & 7);
      aoff[h][m] = row * 64 + p * 8;
      int rowb = wc * 64 + m * 16 + (lane & 15);
      int pb = (h * 4 + (lane >> 4)) ^ (rowb & 7);
      boff[h][m] = rowb * 64 + pb * 8;
    }

  // stage one K-tile (8 global_load_lds of 16B per thread) into buffer b
  auto stage = [&](int b, int k0) {
#pragma unroll
    for (int s = 0; s < 4; ++s) {
      __builtin_amdgcn_global_load_lds(
          (const AS1 unsigned int*)(xbf + asrc[s] + k0),
          (AS3 unsigned int*)(&As[b][s * 2048 + wave * 512]),
          16, 0, 0);
      __builtin_amdgcn_global_load_lds(
          (const AS1 unsigned int*)(wb + bsrc[s] + k0),
          (AS3 unsigned int*)(&Bs[b][s * 2048 + wave * 512]),
          16, 0, 0);
    }
  };

  stage(0, 0);                          // 8 loads in flight
  for (int k = 0; k < 16; ++k) {
    if (k < 15) {
      stage((k + 1) & 1, (k + 1) * 64); // 16 in flight
      asm volatile("s_waitcnt vmcnt(8)" ::: "memory");  // current tile landed
    } else {
      asm volatile("s_waitcnt vmcnt(0)" ::: "memory");
    }
    __builtin_amdgcn_s_barrier();       // raw barrier: no compiler vmcnt(0) drain
    __builtin_amdgcn_sched_barrier(0);
    const unsigned short* Ab = As[k & 1];
    const unsigned short* Bb = Bs[k & 1];
#pragma unroll
    for (int h = 0; h < 2; ++h) {
      bf16x8 af[4], bfr[4];
#pragma unroll
      for (int m = 0; m < 4; ++m) af[m] = *(const bf16x8*)&Ab[aoff[h][m]];
#pragma unroll
      for (int n = 0; n < 4; ++n) bfr[n] = *(const bf16x8*)&Bb[boff[h][n]];
#pragma unroll
      for (int m = 0; m < 4; ++m)
#pragma unroll
        for (int n = 0; n < 4; ++n)
          acc[m][n] = __builtin_amdgcn_mfma_f32_16x16x32_bf16(af[m], bfr[n], acc[m][n], 0, 0, 0);
    }
    __builtin_amdgcn_s_barrier();       // all waves done reading before re-stage
  }

  // Epilogue: C/D layout col = lane&15, row = (lane>>4)*4 + reg. Bias + scatter.
  const int colb = n0 + wc * 64 + (lane & 15);
  float bias[4];
#pragma unroll
  for (int n = 0; n < 4; ++n) bias[n] = eb[(e << 10) + colb + n * 16];
#pragma unroll
  for (int m = 0; m < 4; ++m) {
    int rbase = t * 128 + wr * 64 + m * 16 + ((lane >> 4) << 2);
#pragma unroll
    for (int r = 0; r < 4; ++r) {
      int mm = rbase + r;
      if (mm < c) {
        int g = tok[mm];
        float* op = out + ((size_t)g << 10);
#pragma unroll
        for (int n = 0; n < 4; ++n) op[colb + n * 16] = acc[m][n][r] + bias[n];
      }
    }
  }
}

extern "C" void kernel_launch(void* const* d_in, const int* in_sizes, int n_in,
                              void* d_out, int out_size, void* d_ws, size_t ws_size,
                              hipStream_t stream) {
  const float* x  = (const float*)d_in[0];
  const float* rw = (const float*)d_in[1];
  const float* rb = (const float*)d_in[2];
  const float* ew = (const float*)d_in[3];
  const float* eb = (const float*)d_in[4];
  float* out = (float*)d_out;

  char* ws = (char*)d_ws;
  unsigned short* wbf = (unsigned short*)ws;                         // 16 MB
  unsigned short* xbf = (unsigned short*)(ws + (16u << 20));         // 32 MB
  int* tok    = (int*)(ws + (48u << 20));                            // 512 KB
  int* counts = (int*)(ws + (48u << 20) + (1u << 19));               // 32 B
  int* top    = (int*)(ws + (48u << 20) + (1u << 19) + 128);         // 64 KB

  k_router<<<NTOK / 16, 256, 0, stream>>>(x, rw, rb, xbf, top);      // 1024 blocks
  k_sortconv<<<1025, 1024, 0, stream>>>(ew, wbf, top, counts, tok);  // sort || convw
  k_gemm<<<8192, 256, 0, stream>>>(xbf, wbf, eb, counts, tok, out);
}